// Round 4
// baseline (535.058 us; speedup 1.0000x reference)
//
#include <hip/hip_runtime.h>
#include <hip/hip_bf16.h>
#include <cstdint>
#include <cstddef>

#define DFEAT 128
#define TROWS 48
#define APAD  132   // LDS row stride for A tile (132*4=528 B, float4-aligned, odd bank groups)

// ---------------- CSR build ----------------

__global__ void k_count(const int* __restrict__ src, const int* __restrict__ dst,
                        int* __restrict__ cnt_out, int* __restrict__ cnt_in, int E) {
    int e = blockIdx.x * blockDim.x + threadIdx.x;
    if (e < E) {
        atomicAdd(&cnt_out[src[e]], 1);
        atomicAdd(&cnt_in[dst[e]], 1);
    }
}

// invs from counts; resets cnt_out to 0 so it can be reused as the fill cursor
__global__ void k_invs(int* __restrict__ cnt_out, const int* __restrict__ cnt_in,
                       float* __restrict__ invs_out, float* __restrict__ invs_in, int N) {
    int i = blockIdx.x * blockDim.x + threadIdx.x;
    if (i < N) {
        int co = cnt_out[i];
        int ci = cnt_in[i];
        invs_out[i] = rsqrtf((float)(co > 1 ? co : 1));
        invs_in[i]  = rsqrtf((float)(ci > 1 ? ci : 1));
        cnt_out[i] = 0;
    }
}

// phase 1: per-256-tile exclusive scan of cnt_in into row_ptr, tile sums to tsum
__global__ __launch_bounds__(256) void k_scan1(const int* __restrict__ cnt_in,
                                               int* __restrict__ row_ptr,
                                               int* __restrict__ tsum, int N) {
    __shared__ int s[256];
    int t = threadIdx.x;
    int i = blockIdx.x * 256 + t;
    int v = (i < N) ? cnt_in[i] : 0;
    s[t] = v;
    __syncthreads();
    #pragma unroll
    for (int off = 1; off < 256; off <<= 1) {
        int x = 0;
        if (t >= off) x = s[t - off];
        __syncthreads();
        s[t] += x;
        __syncthreads();
    }
    if (i < N) row_ptr[i] = s[t] - v;            // exclusive within tile
    if (t == 255) tsum[blockIdx.x] = s[255];
}

// phase 2: serial scan of tile sums (nb ~ 391) + writes row_ptr[N]
__global__ void k_scan2(const int* __restrict__ tsum, int* __restrict__ toff,
                        int* __restrict__ row_ptr, int nb, int N) {
    if (blockIdx.x == 0 && threadIdx.x == 0) {
        int run = 0;
        for (int b = 0; b < nb; b++) { toff[b] = run; run += tsum[b]; }
        row_ptr[N] = run;   // == E
    }
}

// phase 3: add tile offsets
__global__ void k_scan3(int* __restrict__ row_ptr, const int* __restrict__ toff, int N) {
    int i = blockIdx.x * 256 + threadIdx.x;
    if (i < N) row_ptr[i] += toff[blockIdx.x];
}

// counting-sort fill: col[row_ptr[d] + cursor[d]++] = src
__global__ void k_fill(const int* __restrict__ src, const int* __restrict__ dst,
                       const int* __restrict__ row_ptr, int* __restrict__ cur,
                       int* __restrict__ col, int E) {
    int e = blockIdx.x * blockDim.x + threadIdx.x;
    if (e < E) {
        int d = dst[e];
        int pos = row_ptr[d] + atomicAdd(&cur[d], 1);
        col[pos] = src[e];
    }
}

// ---------------- fused aggregate (CSR gather) + GEMM + bias (+relu), all f32 ----------------
// 48-row x 128-col tile; 256 threads. LDS: At only = 48*132*4 = 25,344 B.
// W (64 KB f32) read from global: L1/L2-resident, 8x intra-block reuse per element.

template <bool RELU>
__global__ __launch_bounds__(256) void k_fused(
    const float* __restrict__ X, const int* __restrict__ row_ptr,
    const int* __restrict__ col, const float* __restrict__ invs_out,
    const float* __restrict__ invs_in,
    const float* __restrict__ W, const float* __restrict__ bias,
    float* __restrict__ out, int N)
{
    __shared__ float At[TROWS][APAD];

    const int tid  = threadIdx.x;
    const int row0 = blockIdx.x * TROWS;

    // aggregation: wave w -> rows w*12..w*12+11; lane -> feats 2l,2l+1.
    // Row-uniform neighbor loop: no intra-wave divergence, coalesced 512B row gathers.
    {
        const int wave = tid >> 6;
        const int lane = tid & 63;
        const int f = lane * 2;
        for (int i = 0; i < 12; i++) {
            int r = wave * 12 + i;
            int grow = row0 + r;
            float ax = 0.f, ay = 0.f;
            if (grow < N) {
                int jb = row_ptr[grow], je = row_ptr[grow + 1];
                for (int j = jb; j < je; j++) {
                    int s = col[j];
                    float sc = invs_out[s];
                    float2 v = *reinterpret_cast<const float2*>(&X[(size_t)s * DFEAT + f]);
                    ax += v.x * sc;
                    ay += v.y * sc;
                }
                float si = invs_in[grow];
                ax *= si; ay *= si;
            }
            At[r][f]     = ax;
            At[r][f + 1] = ay;
        }
    }
    __syncthreads();

    // GEMM: thread -> 6 rows x 4 cols; A float4 along k from LDS; W float4 from global.
    const int r0 = (tid >> 5) * 6;
    const int c0 = (tid & 31) * 4;

    float acc[6][4];
    #pragma unroll
    for (int i = 0; i < 6; i++)
        #pragma unroll
        for (int j = 0; j < 4; j++) acc[i][j] = 0.0f;

    for (int k4 = 0; k4 < DFEAT; k4 += 4) {
        float4 a[6];
        #pragma unroll
        for (int i = 0; i < 6; i++)
            a[i] = *reinterpret_cast<const float4*>(&At[r0 + i][k4]);
        #pragma unroll
        for (int kk = 0; kk < 4; kk++) {
            float4 w = *reinterpret_cast<const float4*>(&W[(size_t)(k4 + kk) * DFEAT + c0]);
            #pragma unroll
            for (int i = 0; i < 6; i++) {
                float av = (&a[i].x)[kk];
                acc[i][0] += av * w.x;
                acc[i][1] += av * w.y;
                acc[i][2] += av * w.z;
                acc[i][3] += av * w.w;
            }
        }
    }

    float4 bv = *reinterpret_cast<const float4*>(&bias[c0]);

    #pragma unroll
    for (int i = 0; i < 6; i++) {
        int grow = row0 + r0 + i;
        if (grow < N) {
            float4 o;
            o.x = acc[i][0] + bv.x;
            o.y = acc[i][1] + bv.y;
            o.z = acc[i][2] + bv.z;
            o.w = acc[i][3] + bv.w;
            if (RELU) {
                o.x = fmaxf(o.x, 0.f); o.y = fmaxf(o.y, 0.f);
                o.z = fmaxf(o.z, 0.f); o.w = fmaxf(o.w, 0.f);
            }
            *reinterpret_cast<float4*>(&out[(size_t)grow * DFEAT + c0]) = o;
        }
    }
}

// ---------------- launch ----------------

extern "C" void kernel_launch(void* const* d_in, const int* in_sizes, int n_in,
                              void* d_out, int out_size, void* d_ws, size_t ws_size,
                              hipStream_t stream) {
    // inputs: 0:t 1:h 2:src 3:dst 4:W1 5:b1 6:W2 7:b2 — float tensors are FLOAT32
    float* hbuf       = (float*)d_in[1];   // clobbered as layer-2 out; harness restores per launch
    const int* src    = (const int*)d_in[2];
    const int* dst    = (const int*)d_in[3];
    const float* W1   = (const float*)d_in[4];
    const float* b1   = (const float*)d_in[5];
    const float* W2   = (const float*)d_in[6];
    const float* b2   = (const float*)d_in[7];
    float* out        = (float*)d_out;

    const int N = in_sizes[1] / DFEAT;
    const int E = in_sizes[2];
    const size_t ND = (size_t)N * DFEAT;
    const int nb = (N + 255) / 256;

    // workspace (4-byte words), total ~ 5N + 2nb + E + 1 words ~= 4.6 MB
    int* wsi = (int*)d_ws;
    int*   cnt_out  = wsi;                        // N (later: fill cursor)
    int*   cnt_in   = wsi + (size_t)N;            // N
    int*   row_ptr  = wsi + 2 * (size_t)N;        // N+1
    int*   tsum     = wsi + 3 * (size_t)N + 1;    // nb
    int*   toff     = tsum + nb;                  // nb
    float* invs_out = (float*)(toff + nb);        // N
    float* invs_in  = invs_out + N;               // N
    int*   col      = (int*)(invs_in + N);        // E

    // 1. degrees (cnt_out, cnt_in adjacent -> one memset)
    hipMemsetAsync(cnt_out, 0, 2 * (size_t)N * sizeof(int), stream);
    k_count<<<(E + 255) / 256, 256, 0, stream>>>(src, dst, cnt_out, cnt_in, E);
    k_invs<<<nb, 256, 0, stream>>>(cnt_out, cnt_in, invs_out, invs_in, N);

    // 2. CSR by dst
    k_scan1<<<nb, 256, 0, stream>>>(cnt_in, row_ptr, tsum, N);
    k_scan2<<<1, 64, 0, stream>>>(tsum, toff, row_ptr, nb, N);
    k_scan3<<<nb, 256, 0, stream>>>(row_ptr, toff, N);
    k_fill<<<(E + 255) / 256, 256, 0, stream>>>(src, dst, row_ptr, cnt_out, col, E);

    // 3. layer 1: h -> d_out (h1 scratch)
    const int gblocks = (N + TROWS - 1) / TROWS;
    k_fused<true><<<gblocks, 256, 0, stream>>>(
        hbuf, row_ptr, col, invs_out, invs_in, W1, b1, out, N);

    // 4. layer 2: d_out -> hbuf (fully consumed by layer 1; stream-ordered), then copy back
    k_fused<false><<<gblocks, 256, 0, stream>>>(
        out, row_ptr, col, invs_out, invs_in, W2, b2, hbuf, N);
    hipMemcpyAsync(out, hbuf, ND * sizeof(float), hipMemcpyDeviceToDevice, stream);
}

// Round 5
// 390.280 us; speedup vs baseline: 1.3710x; 1.3710x over previous
//
#include <hip/hip_runtime.h>
#include <hip/hip_bf16.h>
#include <cstdint>
#include <cstddef>

#define DFEAT 128
#define TROWS 48
#define APAD  132   // LDS row stride for A tile (132*4=528 B, float4-aligned)

// ---------------- CSR build ----------------

__global__ void k_count(const int* __restrict__ src, const int* __restrict__ dst,
                        int* __restrict__ cnt_out, int* __restrict__ cnt_in, int E) {
    int e = blockIdx.x * blockDim.x + threadIdx.x;
    if (e < E) {
        atomicAdd(&cnt_out[src[e]], 1);
        atomicAdd(&cnt_in[dst[e]], 1);
    }
}

// invs from counts; resets cnt_out to 0 so it can be reused as the fill cursor
__global__ void k_invs(int* __restrict__ cnt_out, const int* __restrict__ cnt_in,
                       float* __restrict__ invs_out, float* __restrict__ invs_in, int N) {
    int i = blockIdx.x * blockDim.x + threadIdx.x;
    if (i < N) {
        int co = cnt_out[i];
        int ci = cnt_in[i];
        invs_out[i] = rsqrtf((float)(co > 1 ? co : 1));
        invs_in[i]  = rsqrtf((float)(ci > 1 ? ci : 1));
        cnt_out[i] = 0;
    }
}

// phase 1: per-256-tile exclusive scan of cnt_in into row_ptr, tile sums to tsum
__global__ __launch_bounds__(256) void k_scan1(const int* __restrict__ cnt_in,
                                               int* __restrict__ row_ptr,
                                               int* __restrict__ tsum, int N) {
    __shared__ int s[256];
    int t = threadIdx.x;
    int i = blockIdx.x * 256 + t;
    int v = (i < N) ? cnt_in[i] : 0;
    s[t] = v;
    __syncthreads();
    #pragma unroll
    for (int off = 1; off < 256; off <<= 1) {
        int x = 0;
        if (t >= off) x = s[t - off];
        __syncthreads();
        s[t] += x;
        __syncthreads();
    }
    if (i < N) row_ptr[i] = s[t] - v;            // exclusive within tile
    if (t == 255) tsum[blockIdx.x] = s[255];
}

// phase 2 (parallel): single-block scan of tile sums (nb <= 1024) + row_ptr[N]
__global__ __launch_bounds__(1024) void k_scan2p(const int* __restrict__ tsum,
                                                 int* __restrict__ toff,
                                                 int* __restrict__ row_ptr, int nb, int N) {
    __shared__ int s[1024];
    int t = threadIdx.x;
    int v = (t < nb) ? tsum[t] : 0;
    s[t] = v;
    __syncthreads();
    #pragma unroll
    for (int off = 1; off < 1024; off <<= 1) {
        int x = (t >= off) ? s[t - off] : 0;
        __syncthreads();
        s[t] += x;
        __syncthreads();
    }
    if (t < nb) toff[t] = s[t] - v;              // exclusive
    if (t == nb - 1) row_ptr[N] = s[t];          // == E
}

// phase 2 fallback (serial) for nb > 1024 — not expected at this size
__global__ void k_scan2s(const int* __restrict__ tsum, int* __restrict__ toff,
                         int* __restrict__ row_ptr, int nb, int N) {
    if (blockIdx.x == 0 && threadIdx.x == 0) {
        int run = 0;
        for (int b = 0; b < nb; b++) { toff[b] = run; run += tsum[b]; }
        row_ptr[N] = run;
    }
}

// phase 3: add tile offsets
__global__ void k_scan3(int* __restrict__ row_ptr, const int* __restrict__ toff, int N) {
    int i = blockIdx.x * 256 + threadIdx.x;
    if (i < N) row_ptr[i] += toff[blockIdx.x];
}

// counting-sort fill: col[row_ptr[d] + cursor[d]++] = src
__global__ void k_fill(const int* __restrict__ src, const int* __restrict__ dst,
                       const int* __restrict__ row_ptr, int* __restrict__ cur,
                       int* __restrict__ col, int E) {
    int e = blockIdx.x * blockDim.x + threadIdx.x;
    if (e < E) {
        int d = dst[e];
        int pos = row_ptr[d] + atomicAdd(&cur[d], 1);
        col[pos] = src[e];
    }
}

// ---------------- fused aggregate (CSR gather) + GEMM + bias (+relu), all f32 ----------------
// 48-row x 128-col tile; 256 threads = 8 groups of 32 lanes.
// Aggregation: group -> one row at a time (float4/lane = full 512B row per load),
// neighbor loop unrolled 4x/2x for 4 independent gathers in flight per group.

template <bool RELU>
__global__ __launch_bounds__(256) void k_fused(
    const float* __restrict__ X, const int* __restrict__ row_ptr,
    const int* __restrict__ col, const float* __restrict__ invs_out,
    const float* __restrict__ invs_in,
    const float* __restrict__ W, const float* __restrict__ bias,
    float* __restrict__ out, int N)
{
    __shared__ float At[TROWS][APAD];

    const int tid  = threadIdx.x;
    const int row0 = blockIdx.x * TROWS;
    const float4* X4 = reinterpret_cast<const float4*>(X);

    // ---- aggregation ----
    {
        const int grp  = tid >> 5;      // 0..7
        const int lane = tid & 31;      // covers feats lane*4 .. lane*4+3
        #pragma unroll
        for (int i = 0; i < 6; i++) {
            int r = grp * 6 + i;
            int grow = row0 + r;
            float4 acc = make_float4(0.f, 0.f, 0.f, 0.f);
            if (grow < N) {
                int jb = row_ptr[grow], je = row_ptr[grow + 1];
                int j = jb;
                for (; j + 3 < je; j += 4) {
                    int s0 = col[j], s1 = col[j + 1], s2 = col[j + 2], s3 = col[j + 3];
                    float c0 = invs_out[s0], c1 = invs_out[s1];
                    float c2 = invs_out[s2], c3 = invs_out[s3];
                    float4 v0 = X4[(size_t)s0 * 32 + lane];
                    float4 v1 = X4[(size_t)s1 * 32 + lane];
                    float4 v2 = X4[(size_t)s2 * 32 + lane];
                    float4 v3 = X4[(size_t)s3 * 32 + lane];
                    acc.x += v0.x * c0 + v1.x * c1 + v2.x * c2 + v3.x * c3;
                    acc.y += v0.y * c0 + v1.y * c1 + v2.y * c2 + v3.y * c3;
                    acc.z += v0.z * c0 + v1.z * c1 + v2.z * c2 + v3.z * c3;
                    acc.w += v0.w * c0 + v1.w * c1 + v2.w * c2 + v3.w * c3;
                }
                for (; j + 1 < je; j += 2) {
                    int s0 = col[j], s1 = col[j + 1];
                    float c0 = invs_out[s0], c1 = invs_out[s1];
                    float4 v0 = X4[(size_t)s0 * 32 + lane];
                    float4 v1 = X4[(size_t)s1 * 32 + lane];
                    acc.x += v0.x * c0 + v1.x * c1;
                    acc.y += v0.y * c0 + v1.y * c1;
                    acc.z += v0.z * c0 + v1.z * c1;
                    acc.w += v0.w * c0 + v1.w * c1;
                }
                if (j < je) {
                    int s0 = col[j];
                    float c0 = invs_out[s0];
                    float4 v0 = X4[(size_t)s0 * 32 + lane];
                    acc.x += v0.x * c0; acc.y += v0.y * c0;
                    acc.z += v0.z * c0; acc.w += v0.w * c0;
                }
                float si = invs_in[grow];
                acc.x *= si; acc.y *= si; acc.z *= si; acc.w *= si;
            }
            *reinterpret_cast<float4*>(&At[r][lane * 4]) = acc;
        }
    }
    __syncthreads();

    // ---- GEMM: thread -> 6 rows x 4 cols; A float4 from LDS; W float4 from global (L1) ----
    const int r0 = (tid >> 5) * 6;
    const int c0 = (tid & 31) * 4;

    float acc[6][4];
    #pragma unroll
    for (int i = 0; i < 6; i++)
        #pragma unroll
        for (int j = 0; j < 4; j++) acc[i][j] = 0.0f;

    for (int k4 = 0; k4 < DFEAT; k4 += 4) {
        float4 a[6];
        #pragma unroll
        for (int i = 0; i < 6; i++)
            a[i] = *reinterpret_cast<const float4*>(&At[r0 + i][k4]);
        #pragma unroll
        for (int kk = 0; kk < 4; kk++) {
            float4 w = *reinterpret_cast<const float4*>(&W[(size_t)(k4 + kk) * DFEAT + c0]);
            #pragma unroll
            for (int i = 0; i < 6; i++) {
                float av = (&a[i].x)[kk];
                acc[i][0] += av * w.x;
                acc[i][1] += av * w.y;
                acc[i][2] += av * w.z;
                acc[i][3] += av * w.w;
            }
        }
    }

    float4 bv = *reinterpret_cast<const float4*>(&bias[c0]);

    #pragma unroll
    for (int i = 0; i < 6; i++) {
        int grow = row0 + r0 + i;
        if (grow < N) {
            float4 o;
            o.x = acc[i][0] + bv.x;
            o.y = acc[i][1] + bv.y;
            o.z = acc[i][2] + bv.z;
            o.w = acc[i][3] + bv.w;
            if (RELU) {
                o.x = fmaxf(o.x, 0.f); o.y = fmaxf(o.y, 0.f);
                o.z = fmaxf(o.z, 0.f); o.w = fmaxf(o.w, 0.f);
            }
            *reinterpret_cast<float4*>(&out[(size_t)grow * DFEAT + c0]) = o;
        }
    }
}

// ---------------- launch ----------------

extern "C" void kernel_launch(void* const* d_in, const int* in_sizes, int n_in,
                              void* d_out, int out_size, void* d_ws, size_t ws_size,
                              hipStream_t stream) {
    // inputs: 0:t 1:h 2:src 3:dst 4:W1 5:b1 6:W2 7:b2 — float tensors are FLOAT32
    float* hbuf       = (float*)d_in[1];   // may be clobbered (harness restores per launch)
    const int* src    = (const int*)d_in[2];
    const int* dst    = (const int*)d_in[3];
    const float* W1   = (const float*)d_in[4];
    const float* b1   = (const float*)d_in[5];
    const float* W2   = (const float*)d_in[6];
    const float* b2   = (const float*)d_in[7];
    float* out        = (float*)d_out;

    const int N = in_sizes[1] / DFEAT;
    const int E = in_sizes[2];
    const size_t ND = (size_t)N * DFEAT;
    const int nb = (N + 255) / 256;

    // workspace (4-byte words): CSR + norms ~= 4.6 MB, then optionally h1 (ND f32)
    int* wsi = (int*)d_ws;
    int*   cnt_out  = wsi;                        // N (later: fill cursor)
    int*   cnt_in   = wsi + (size_t)N;            // N
    int*   row_ptr  = wsi + 2 * (size_t)N;        // N+1
    int*   tsum     = wsi + 3 * (size_t)N + 1;    // nb
    int*   toff     = tsum + nb;                  // nb
    float* invs_out = (float*)(toff + nb);        // N
    float* invs_in  = invs_out + N;               // N
    int*   col      = (int*)(invs_in + N);        // E
    size_t base_words = 5 * (size_t)N + 1 + 2 * (size_t)nb + (size_t)E;
    base_words = (base_words + 3) & ~(size_t)3;   // 16B align
    float* h1w = (float*)wsi + base_words;        // ND f32 (if it fits)
    const bool h1_in_ws = ws_size >= (base_words + ND) * sizeof(float);

    // 1. degrees (cnt_out, cnt_in adjacent -> one memset)
    hipMemsetAsync(cnt_out, 0, 2 * (size_t)N * sizeof(int), stream);
    k_count<<<(E + 255) / 256, 256, 0, stream>>>(src, dst, cnt_out, cnt_in, E);
    k_invs<<<nb, 256, 0, stream>>>(cnt_out, cnt_in, invs_out, invs_in, N);

    // 2. CSR by dst
    k_scan1<<<nb, 256, 0, stream>>>(cnt_in, row_ptr, tsum, N);
    if (nb <= 1024)
        k_scan2p<<<1, 1024, 0, stream>>>(tsum, toff, row_ptr, nb, N);
    else
        k_scan2s<<<1, 64, 0, stream>>>(tsum, toff, row_ptr, nb, N);
    k_scan3<<<nb, 256, 0, stream>>>(row_ptr, toff, N);
    k_fill<<<(E + 255) / 256, 256, 0, stream>>>(src, dst, row_ptr, cnt_out, col, E);

    // 3. two fused layers
    const int gblocks = (N + TROWS - 1) / TROWS;
    if (h1_in_ws) {
        // h1 lives in ws; layer 2 writes d_out directly; no memcpy, input untouched
        k_fused<true><<<gblocks, 256, 0, stream>>>(
            hbuf, row_ptr, col, invs_out, invs_in, W1, b1, h1w, N);
        k_fused<false><<<gblocks, 256, 0, stream>>>(
            h1w, row_ptr, col, invs_out, invs_in, W2, b2, out, N);
    } else {
        // ping-pong through d_out and the (restorable) input buffer
        k_fused<true><<<gblocks, 256, 0, stream>>>(
            hbuf, row_ptr, col, invs_out, invs_in, W1, b1, out, N);
        k_fused<false><<<gblocks, 256, 0, stream>>>(
            out, row_ptr, col, invs_out, invs_in, W2, b2, hbuf, N);
        hipMemcpyAsync(out, hbuf, ND * sizeof(float), hipMemcpyDeviceToDevice, stream);
    }
}